// Round 1
// baseline (1215.312 us; speedup 1.0000x reference)
//
#include <hip/hip_runtime.h>
#include <hip/hip_bf16.h>

// Problem constants
#define BB 4
#define NCC 1792
#define NTT 256
#define NN 2048        // NCC + NTT
#define DMv 256
#define DIv 512
#define DSv 16
#define DTRv 16
#define KK 4
#define LL 4
#define NTOK (BB*NN)   // 8192

#define CCH 32         // chunks for scan
#define CL  64         // chunk length = NN/CCH

__device__ __forceinline__ float siluf(float x) {
    return x / (1.f + __expf(-x));
}
__device__ __forceinline__ float softplusf(float x) {
    return fmaxf(x, 0.f) + log1pf(__expf(-fabsf(x)));
}

// ---------------------------------------------------------------------------
// Embedding: tokens = [x_t, y_{t-1}, 0]; z = relu(tokens@We1+be1)@We2+be2
// one block per token, 256 threads (one per DM dim)
// ---------------------------------------------------------------------------
__global__ __launch_bounds__(256) void embed_kernel(
    const float* __restrict__ xc, const float* __restrict__ yc,
    const float* __restrict__ xt, const float* __restrict__ yt,
    const float* __restrict__ We1, const float* __restrict__ be1,
    const float* __restrict__ We2, const float* __restrict__ be2,
    float* __restrict__ z)
{
    int token = blockIdx.x;
    int b = token / NN, t = token % NN;
    int d = threadIdx.x;

    float xv = (t < NCC) ? xc[b*NCC + t] : xt[b*NTT + (t - NCC)];
    float yprev = 0.f;
    if (t > 0) {
        int tp = t - 1;
        yprev = (tp < NCC) ? yc[b*NCC + tp] : yt[b*NTT + (tp - NCC)];
    }
    __shared__ float h1[DMv];
    float h = xv * We1[0*DMv + d] + yprev * We1[1*DMv + d] + be1[d];
    h1[d] = fmaxf(h, 0.f);
    __syncthreads();

    float acc = be2[d];
    #pragma unroll 8
    for (int k = 0; k < DMv; k++) acc += h1[k] * We2[k*DMv + d];
    z[(long)token*DMv + d] = acc;
}

// ---------------------------------------------------------------------------
// RMSNorm over DM=256: one block per token
// ---------------------------------------------------------------------------
__global__ __launch_bounds__(256) void rmsnorm_kernel(
    const float* __restrict__ z, const float* __restrict__ nw, float* __restrict__ xn)
{
    int token = blockIdx.x;
    int d = threadIdx.x;
    float v = z[(long)token*DMv + d];
    float ss = v * v;
    #pragma unroll
    for (int m = 32; m >= 1; m >>= 1) ss += __shfl_xor(ss, m, 64);
    __shared__ float red[4];
    int wid = threadIdx.x >> 6;
    if ((threadIdx.x & 63) == 0) red[wid] = ss;
    __syncthreads();
    float tot = red[0] + red[1] + red[2] + red[3];
    float scale = rsqrtf(tot * (1.f/DMv) + 1e-5f);
    xn[(long)token*DMv + d] = v * scale * nw[d];
}

// ---------------------------------------------------------------------------
// fp32 GEMM: C[M,N] (+=res? in-place) = A[M,K] @ B[K,N]
// 256 threads, BMxBN tile, TMxTN microtile
// ---------------------------------------------------------------------------
template<int BM, int BN, int BK, int TM, int TN, bool RES>
__global__ __launch_bounds__(256) void gemm_kernel(
    const float* __restrict__ A, const float* __restrict__ B,
    float* __restrict__ Cmat, int M, int N, int K)
{
    constexpr int TX = BN / TN;   // threads along n
    constexpr int TY = BM / TM;   // threads along m
    static_assert(TX * TY == 256, "bad cfg");

    __shared__ float As[BK][BM + 4];
    __shared__ float Bs[BK][BN + 4];

    int tid = threadIdx.x;
    int tx = tid % TX, ty = tid / TX;
    int bm0 = blockIdx.y * BM, bn0 = blockIdx.x * BN;

    float acc[TM][TN];
    #pragma unroll
    for (int i = 0; i < TM; i++)
        #pragma unroll
        for (int j = 0; j < TN; j++) acc[i][j] = 0.f;

    for (int k0 = 0; k0 < K; k0 += BK) {
        // A tile: BM x BK  (stored transposed As[k][m])
        #pragma unroll
        for (int i = tid; i < BM*BK/4; i += 256) {
            int m  = i / (BK/4);
            int k4 = i % (BK/4);
            float4 v = *(const float4*)&A[(long)(bm0 + m)*K + k0 + k4*4];
            As[k4*4+0][m] = v.x; As[k4*4+1][m] = v.y;
            As[k4*4+2][m] = v.z; As[k4*4+3][m] = v.w;
        }
        // B tile: BK x BN
        #pragma unroll
        for (int i = tid; i < BK*BN/4; i += 256) {
            int k  = i / (BN/4);
            int n4 = i % (BN/4);
            *(float4*)&Bs[k][n4*4] = *(const float4*)&B[(long)(k0 + k)*N + bn0 + n4*4];
        }
        __syncthreads();

        #pragma unroll
        for (int k = 0; k < BK; k++) {
            float a[TM], bb[TN];
            #pragma unroll
            for (int i = 0; i < TM; i += 4) {
                float4 v = *(const float4*)&As[k][ty*TM + i];
                a[i] = v.x; a[i+1] = v.y; a[i+2] = v.z; a[i+3] = v.w;
            }
            #pragma unroll
            for (int j = 0; j < TN; j += 4) {
                float4 v = *(const float4*)&Bs[k][tx*TN + j];
                bb[j] = v.x; bb[j+1] = v.y; bb[j+2] = v.z; bb[j+3] = v.w;
            }
            #pragma unroll
            for (int i = 0; i < TM; i++)
                #pragma unroll
                for (int j = 0; j < TN; j++)
                    acc[i][j] = fmaf(a[i], bb[j], acc[i][j]);
        }
        __syncthreads();
    }

    #pragma unroll
    for (int i = 0; i < TM; i++) {
        #pragma unroll
        for (int j = 0; j < TN; j += 4) {
            long off = (long)(bm0 + ty*TM + i)*N + bn0 + tx*TN + j;
            float4 v;
            v.x = acc[i][j]; v.y = acc[i][j+1]; v.z = acc[i][j+2]; v.w = acc[i][j+3];
            if (RES) {
                float4 r = *(const float4*)&Cmat[off];
                v.x += r.x; v.y += r.y; v.z += r.z; v.w += r.w;
            }
            *(float4*)&Cmat[off] = v;
        }
    }
}

// ---------------------------------------------------------------------------
// Depthwise causal conv (K=4) + bias + SiLU on u half of ug
// thread per (token, di)
// ---------------------------------------------------------------------------
__global__ __launch_bounds__(256) void conv_silu_kernel(
    const float* __restrict__ ug, const float* __restrict__ Wc,
    const float* __restrict__ bc, float* __restrict__ uc)
{
    int idx = blockIdx.x * 256 + threadIdx.x;   // token*512 + di
    int di = idx & (DIv - 1);
    int token = idx >> 9;
    int t = token & (NN - 1);

    float acc = bc[di];
    #pragma unroll
    for (int j = 0; j < KK; j++) {
        int tt = t - (KK-1) + j;
        if (tt >= 0)
            acc = fmaf(ug[((long)(token - (KK-1) + j) << 10) + di], Wc[di*KK + j], acc);
    }
    uc[idx] = siluf(acc);
}

// ---------------------------------------------------------------------------
// dbl = u @ Wx (512 -> 48); store Bm,Cm; delta = softplus(dt@Wdt + bdt)
// one block (64 threads) per token
// ---------------------------------------------------------------------------
__global__ __launch_bounds__(64) void proj_delta_kernel(
    const float* __restrict__ uc, const float* __restrict__ Wx,
    const float* __restrict__ Wdt, const float* __restrict__ bdt,
    float* __restrict__ bc2, float* __restrict__ delta)
{
    int token = blockIdx.x;
    int lane = threadIdx.x;
    __shared__ float us[DIv];
    __shared__ float dts[DTRv];

    #pragma unroll
    for (int i = 0; i < DIv/64; i++)
        us[lane + i*64] = uc[(long)token*DIv + lane + i*64];
    __syncthreads();

    if (lane < 48) {
        float a0 = 0.f, a1 = 0.f, a2 = 0.f, a3 = 0.f;
        for (int k = 0; k < DIv; k += 4) {
            a0 = fmaf(us[k+0], Wx[(k+0)*48 + lane], a0);
            a1 = fmaf(us[k+1], Wx[(k+1)*48 + lane], a1);
            a2 = fmaf(us[k+2], Wx[(k+2)*48 + lane], a2);
            a3 = fmaf(us[k+3], Wx[(k+3)*48 + lane], a3);
        }
        float acc = (a0 + a1) + (a2 + a3);
        if (lane < DTRv) dts[lane] = acc;
        else bc2[(long)token*32 + (lane - DTRv)] = acc;
    }
    __syncthreads();

    #pragma unroll
    for (int r = 0; r < DIv/64; r++) {
        int di = r*64 + lane;
        float a = bdt[di];
        #pragma unroll
        for (int k = 0; k < DTRv; k++) a = fmaf(dts[k], Wdt[k*DIv + di], a);
        delta[(long)token*DIv + di] = softplusf(a);
    }
}

// ---------------------------------------------------------------------------
// Scan pass A: per-chunk local scan (h_init=0) -> P (decay product), h_final
// grid (half, chunk, b), 256 threads; thread holds 16 states
// ---------------------------------------------------------------------------
__global__ __launch_bounds__(256) void scanA_kernel(
    const float* __restrict__ delta, const float* __restrict__ uc,
    const float* __restrict__ bc2, const float* __restrict__ Alog,
    float* __restrict__ Pbuf, float* __restrict__ hfin)
{
    int half = blockIdx.x, c = blockIdx.y, b = blockIdx.z;
    int di = half*256 + threadIdx.x;

    float A[DSv], h[DSv], P[DSv];
    #pragma unroll
    for (int s = 0; s < DSv; s++) {
        A[s] = -__expf(Alog[di*DSv + s]);
        h[s] = 0.f; P[s] = 1.f;
    }

    __shared__ float Bsh[CL][DSv];
    int t0 = c * CL;
    for (int i = threadIdx.x; i < CL*DSv; i += 256) {
        int tt = i / DSv, s = i % DSv;
        Bsh[tt][s] = bc2[((long)(b*NN + t0 + tt))*32 + s];
    }
    __syncthreads();

    for (int tt = 0; tt < CL; tt++) {
        long token = (long)b*NN + t0 + tt;
        float d  = delta[token*DIv + di];
        float du = d * uc[token*DIv + di];
        #pragma unroll
        for (int s = 0; s < DSv; s++) {
            float a = __expf(d * A[s]);
            P[s] *= a;
            h[s] = fmaf(a, h[s], du * Bsh[tt][s]);
        }
    }
    long base = (((long)c*BB + b)*DIv + di)*DSv;
    #pragma unroll
    for (int s = 0; s < DSv; s++) { Pbuf[base+s] = P[s]; hfin[base+s] = h[s]; }
}

// ---------------------------------------------------------------------------
// Scan pass B: sequential over chunks -> chunk-initial states
// thread per (b,di,s) = 32768 threads
// ---------------------------------------------------------------------------
__global__ __launch_bounds__(256) void scanB_kernel(
    const float* __restrict__ Pbuf, const float* __restrict__ hfin,
    float* __restrict__ Hinit)
{
    int id = blockIdx.x * 256 + threadIdx.x;  // (b*512+di)*16+s
    float H = 0.f;
    for (int c = 0; c < CCH; c++) {
        long idx = (long)c * (BB*DIv*DSv) + id;
        Hinit[idx] = H;
        H = fmaf(Pbuf[idx], H, hfin[idx]);
    }
}

// ---------------------------------------------------------------------------
// Scan pass C: re-scan with correct init, produce y
// ---------------------------------------------------------------------------
__global__ __launch_bounds__(256) void scanC_kernel(
    const float* __restrict__ delta, const float* __restrict__ uc,
    const float* __restrict__ bc2, const float* __restrict__ Alog,
    const float* __restrict__ Hinit, float* __restrict__ ys)
{
    int half = blockIdx.x, c = blockIdx.y, b = blockIdx.z;
    int di = half*256 + threadIdx.x;

    float A[DSv], h[DSv];
    long base = (((long)c*BB + b)*DIv + di)*DSv;
    #pragma unroll
    for (int s = 0; s < DSv; s++) {
        A[s] = -__expf(Alog[di*DSv + s]);
        h[s] = Hinit[base + s];
    }

    __shared__ float Bsh[CL][DSv];
    __shared__ float Csh[CL][DSv];
    int t0 = c * CL;
    for (int i = threadIdx.x; i < CL*DSv; i += 256) {
        int tt = i / DSv, s = i % DSv;
        long tok = (long)(b*NN + t0 + tt) * 32;
        Bsh[tt][s] = bc2[tok + s];
        Csh[tt][s] = bc2[tok + DSv + s];
    }
    __syncthreads();

    for (int tt = 0; tt < CL; tt++) {
        long token = (long)b*NN + t0 + tt;
        float d  = delta[token*DIv + di];
        float du = d * uc[token*DIv + di];
        float y = 0.f;
        #pragma unroll
        for (int s = 0; s < DSv; s++) {
            float a = __expf(d * A[s]);
            h[s] = fmaf(a, h[s], du * Bsh[tt][s]);
            y = fmaf(h[s], Csh[tt][s], y);
        }
        ys[token*DIv + di] = y;
    }
}

// ---------------------------------------------------------------------------
// yg = (ys + D*u) * silu(gate)
// ---------------------------------------------------------------------------
__global__ __launch_bounds__(256) void gate_kernel(
    const float* __restrict__ ys, const float* __restrict__ uc,
    const float* __restrict__ ug, const float* __restrict__ Dp,
    float* __restrict__ yg)
{
    int idx = blockIdx.x * 256 + threadIdx.x;   // token*512+di
    int di = idx & (DIv - 1);
    long token = idx >> 9;
    float g = ug[(token << 10) + DIv + di];
    float y = fmaf(Dp[di], uc[idx], ys[idx]) * siluf(g);
    yg[idx] = y;
}

// ---------------------------------------------------------------------------
extern "C" void kernel_launch(void* const* d_in, const int* in_sizes, int n_in,
                              void* d_out, int out_size, void* d_ws, size_t ws_size,
                              hipStream_t stream)
{
    const float* xc     = (const float*)d_in[0];
    const float* yc     = (const float*)d_in[1];
    const float* xt     = (const float*)d_in[2];
    const float* yt     = (const float*)d_in[3];
    const float* We1    = (const float*)d_in[4];
    const float* be1    = (const float*)d_in[5];
    const float* We2    = (const float*)d_in[6];
    const float* be2    = (const float*)d_in[7];
    const float* norm_w = (const float*)d_in[8];
    const float* W_in   = (const float*)d_in[9];
    const float* W_conv = (const float*)d_in[10];
    const float* b_conv = (const float*)d_in[11];
    const float* W_xproj= (const float*)d_in[12];
    const float* W_dt   = (const float*)d_in[13];
    const float* b_dt   = (const float*)d_in[14];
    const float* A_log  = (const float*)d_in[15];
    const float* Dp     = (const float*)d_in[16];
    const float* W_out  = (const float*)d_in[17];

    float* z  = (float*)d_out;               // (B,N,DM) updated in place
    float* ws = (float*)d_ws;

    float* xn    = ws;                       // 8192*256
    float* ug    = xn    + (long)NTOK*DMv;   // 8192*1024
    float* uc    = ug    + (long)NTOK*2*DIv; // 8192*512
    float* delta = uc    + (long)NTOK*DIv;   // 8192*512 (reused as yg)
    float* bc2   = delta + (long)NTOK*DIv;   // 8192*32
    float* ysb   = bc2   + (long)NTOK*32;    // 8192*512
    float* Pbuf  = ysb   + (long)NTOK*DIv;   // 32*32768
    float* hfin  = Pbuf  + (long)CCH*BB*DIv*DSv;
    float* Hinit = hfin  + (long)CCH*BB*DIv*DSv;

    embed_kernel<<<NTOK, 256, 0, stream>>>(xc, yc, xt, yt, We1, be1, We2, be2, z);

    for (int l = 0; l < LL; l++) {
        rmsnorm_kernel<<<NTOK, 256, 0, stream>>>(z, norm_w + l*DMv, xn);

        gemm_kernel<128,128,16,8,8,false><<<dim3(2*DIv/128, NTOK/128), 256, 0, stream>>>(
            xn, W_in + (long)l*DMv*2*DIv, ug, NTOK, 2*DIv, DMv);

        conv_silu_kernel<<<NTOK*DIv/256, 256, 0, stream>>>(
            ug, W_conv + l*DIv*KK, b_conv + l*DIv, uc);

        proj_delta_kernel<<<NTOK, 64, 0, stream>>>(
            uc, W_xproj + l*DIv*48, W_dt + l*DTRv*DIv, b_dt + l*DIv, bc2, delta);

        scanA_kernel<<<dim3(2, CCH, BB), 256, 0, stream>>>(
            delta, uc, bc2, A_log + l*DIv*DSv, Pbuf, hfin);

        scanB_kernel<<<BB*DIv*DSv/256, 256, 0, stream>>>(Pbuf, hfin, Hinit);

        scanC_kernel<<<dim3(2, CCH, BB), 256, 0, stream>>>(
            delta, uc, bc2, A_log + l*DIv*DSv, Hinit, ysb);

        gate_kernel<<<NTOK*DIv/256, 256, 0, stream>>>(ysb, uc, ug, Dp + l*DIv, delta);

        gemm_kernel<64,128,16,4,8,true><<<dim3(DMv/128, NTOK/64), 256, 0, stream>>>(
            delta, W_out + (long)l*DIv*DMv, z, NTOK, DMv, DIv);
    }
}